// Round 1
// baseline (401.559 us; speedup 1.0000x reference)
//
#include <hip/hip_runtime.h>
#include <hip/hip_bf16.h>

#define BN 8
#define LN 4096
#define HN 2048
#define EN 512
#define KN 64

#define BH 128   // h rows per block (kernel 2)
#define BE 256   // e cols per block (kernel 2)
#define LT 32    // l tile (K dim of PV mfma)

typedef __attribute__((ext_vector_type(8))) short bf16x8;
typedef __attribute__((ext_vector_type(4))) float f32x4;
typedef __attribute__((ext_vector_type(4))) int i32x4;

union FragU { bf16x8 f; i32x4 i; };

__device__ __forceinline__ short f2b(float x) {
  union { float f; unsigned u; } v; v.f = x;
  unsigned r = v.u + 0x7fffu + ((v.u >> 16) & 1u);  // RNE f32->bf16
  return (short)(r >> 16);
}

__device__ __forceinline__ bf16x8 cvt8(const float* __restrict__ p) {
  f32x4 a = *(const f32x4*)(p);
  f32x4 b = *(const f32x4*)(p + 4);
  bf16x8 r;
  r[0] = f2b(a[0]); r[1] = f2b(a[1]); r[2] = f2b(a[2]); r[3] = f2b(a[3]);
  r[4] = f2b(b[0]); r[5] = f2b(b[1]); r[6] = f2b(b[2]); r[7] = f2b(b[3]);
  return r;
}

// ---------------- Kernel 1: per-(b,l) softmax stats m, 1/Z over H ----------
// grid (L/64, B), block 256 (4 waves). Wave w owns 16 l-rows.
// S[l][h]: A=x (M=l,K=k), B[k][h]=y[h][k]. D: col=lane&15=h, row=4g+r=l.
__global__ __launch_bounds__(256) void k_stats(const float* __restrict__ xd,
                                               const float* __restrict__ yd,
                                               float* __restrict__ mz) {
  const int b = blockIdx.y;
  const int w = threadIdx.x >> 6;
  const int lane = threadIdx.x & 63;
  const int row = lane & 15, g = lane >> 4;
  const int lb = blockIdx.x * 64 + w * 16;

  const float* xp = xd + ((size_t)b * LN + lb + row) * KN + g * 8;
  bf16x8 a0 = cvt8(xp), a1 = cvt8(xp + 32);

  float m[4], s[4];
#pragma unroll
  for (int r = 0; r < 4; ++r) { m[r] = -1e30f; s[r] = 0.f; }

  const float* yb = yd + ((size_t)b * HN + row) * KN + g * 8;
  for (int h0 = 0; h0 < HN; h0 += 16) {
    bf16x8 b0 = cvt8(yb + (size_t)h0 * KN);
    bf16x8 b1 = cvt8(yb + (size_t)h0 * KN + 32);
    f32x4 acc = {0.f, 0.f, 0.f, 0.f};
    acc = __builtin_amdgcn_mfma_f32_16x16x32_bf16(a0, b0, acc, 0, 0, 0);
    acc = __builtin_amdgcn_mfma_f32_16x16x32_bf16(a1, b1, acc, 0, 0, 0);
#pragma unroll
    for (int r = 0; r < 4; ++r) {
      float v = acc[r] * 0.125f;           // scale = 1/sqrt(64)
      float mn = fmaxf(m[r], v);
      s[r] = s[r] * __expf(m[r] - mn) + __expf(v - mn);
      m[r] = mn;
    }
  }
  // merge across the 16 lanes (lane&15) holding different h-columns
#pragma unroll
  for (int d = 1; d < 16; d <<= 1) {
#pragma unroll
    for (int r = 0; r < 4; ++r) {
      float mo = __shfl_xor(m[r], d);
      float so = __shfl_xor(s[r], d);
      float mn = fmaxf(m[r], mo);
      s[r] = s[r] * __expf(m[r] - mn) + so * __expf(mo - mn);
      m[r] = mn;
    }
  }
  if (row == 0) {
#pragma unroll
    for (int r = 0; r < 4; ++r) {
      size_t idx = (size_t)b * LN + lb + 4 * g + r;
      mz[idx] = m[r];
      mz[(size_t)BN * LN + idx] = 1.0f / s[r];
    }
  }
}

// ---------------- Kernel 2: V[b,h,e] = sum_l P^T[h,l] * values[l,e] --------
// grid (H/BH, E/BE, B), block 512 (8 waves). Wave w: h rows [w*16,+16), all BE.
// Phase 1 per l-tile: S^T[h][l] via mfma(A=y, B[k][l]=x[l][k]); P=exp(.)*rz -> pT LDS.
// Phase 2: acc[n] += mfma(A=pT[h][l], B[l][e]=vT[e][l]).
__global__ __launch_bounds__(512) void k_main(const float* __restrict__ vals,
                                              const float* __restrict__ xd,
                                              const float* __restrict__ yd,
                                              const float* __restrict__ mz,
                                              float* __restrict__ out) {
  __shared__ short vT[BE][34];   // [e_local][l], stride 34 (68B rows -> conflict-light scalar transpose)
  __shared__ short pT[BH][34];   // [h_local][l]
  __shared__ short xT[LT][72];   // [l][k], 144B rows (16B aligned for b128 reads)
  __shared__ float smm[LT], smz[LT];

  const int b = blockIdx.z;
  const int hb = blockIdx.x * BH;
  const int eb = blockIdx.y * BE;
  const int tid = threadIdx.x;
  const int w = tid >> 6, lane = tid & 63;
  const int row = lane & 15, g = lane >> 4;

  // y A-frags for this wave's h rows (loop-invariant)
  const float* yp = yd + ((size_t)b * HN + hb + w * 16 + row) * KN + g * 8;
  bf16x8 ya0 = cvt8(yp), ya1 = cvt8(yp + 32);

  f32x4 acc[16];
#pragma unroll
  for (int n = 0; n < 16; ++n) acc[n] = (f32x4){0.f, 0.f, 0.f, 0.f};

  const float* mzb = mz + (size_t)b * LN;
  const float* rzb = mz + (size_t)BN * LN + (size_t)b * LN;

  for (int l0 = 0; l0 < LN; l0 += LT) {
    __syncthreads();  // previous iteration's LDS reads complete

    // ---- stage xT (32 x 64 f32 -> bf16) ----
    {
      int xl = tid >> 4, xk = (tid & 15) * 4;
      f32x4 xv = *(const f32x4*)(xd + ((size_t)b * LN + l0 + xl) * KN + xk);
      union { short h[4]; int i[2]; } u;
      u.h[0] = f2b(xv[0]); u.h[1] = f2b(xv[1]); u.h[2] = f2b(xv[2]); u.h[3] = f2b(xv[3]);
      int* dst = (int*)(&xT[xl][xk]);
      dst[0] = u.i[0]; dst[1] = u.i[1];
    }
    // ---- stage vT transposed: thread writes consecutive-e column slices ----
#pragma unroll
    for (int lp = 0; lp < 4; ++lp) {
      int vl = (tid >> 6) + lp * 8;
      const float* vrow = vals + ((size_t)b * LN + l0 + vl) * EN + eb;
#pragma unroll
      for (int u2 = 0; u2 < 4; ++u2) {
        int e = (tid & 63) + u2 * 64;
        vT[e][vl] = f2b(vrow[e]);
      }
    }
    if (tid < LT) { smm[tid] = mzb[l0 + tid]; smz[tid] = rzb[l0 + tid]; }
    __syncthreads();

    // ---- MFMA1: S^T tiles + P -> pT ----
#pragma unroll
    for (int t = 0; t < 2; ++t) {
      const short* xr = &xT[t * 16 + row][0];
      bf16x8 xb0 = *(const bf16x8*)(xr + 8 * g);
      bf16x8 xb1 = *(const bf16x8*)(xr + 32 + 8 * g);
      f32x4 sa = {0.f, 0.f, 0.f, 0.f};
      sa = __builtin_amdgcn_mfma_f32_16x16x32_bf16(ya0, xb0, sa, 0, 0, 0);
      sa = __builtin_amdgcn_mfma_f32_16x16x32_bf16(ya1, xb1, sa, 0, 0, 0);
      int lcol = t * 16 + row;
      float mm = smm[lcol], zz = smz[lcol];
#pragma unroll
      for (int r = 0; r < 4; ++r) {
        float p = __expf(sa[r] * 0.125f - mm) * zz;
        pT[w * 16 + 4 * g + r][lcol] = f2b(p);
      }
    }
    __syncthreads();

    // ---- MFMA2: acc[n] += P^T x values ----
    FragU pa;
    {
      const int* pi = (const int*)(&pT[w * 16 + row][0] + 8 * g);
      pa.i[0] = pi[0]; pa.i[1] = pi[1]; pa.i[2] = pi[2]; pa.i[3] = pi[3];
    }
#pragma unroll
    for (int n = 0; n < 16; ++n) {
      FragU vb;
      const int* vi = (const int*)(&vT[n * 16 + row][0] + 8 * g);
      vb.i[0] = vi[0]; vb.i[1] = vi[1]; vb.i[2] = vi[2]; vb.i[3] = vi[3];
      acc[n] = __builtin_amdgcn_mfma_f32_16x16x32_bf16(pa.f, vb.f, acc[n], 0, 0, 0);
    }
  }

  // ---- epilogue: D layout col=lane&15 (e), row=4g+r (h) ----
#pragma unroll
  for (int n = 0; n < 16; ++n) {
#pragma unroll
    for (int r = 0; r < 4; ++r) {
      int h = hb + w * 16 + 4 * g + r;
      int e = eb + n * 16 + row;
      out[((size_t)b * HN + h) * EN + e] = acc[n][r];
    }
  }
}

extern "C" void kernel_launch(void* const* d_in, const int* in_sizes, int n_in,
                              void* d_out, int out_size, void* d_ws, size_t ws_size,
                              hipStream_t stream) {
  // inputs: 0 queries (unused), 1 keys (unused), 2 values, 3 x_date, 4 y_date
  const float* values = (const float*)d_in[2];
  const float* xd = (const float*)d_in[3];
  const float* yd = (const float*)d_in[4];
  float* out = (float*)d_out;
  float* mz = (float*)d_ws;  // [2][B][L] f32: m then 1/Z (256 KB)

  dim3 g1(LN / 64, BN);
  k_stats<<<g1, 256, 0, stream>>>(xd, yd, mz);

  dim3 g2(HN / BH, EN / BE, BN);
  k_main<<<g2, 512, 0, stream>>>(values, xd, yd, mz, out);
}

// Round 2
// 197.555 us; speedup vs baseline: 2.0326x; 2.0326x over previous
//
#include <hip/hip_runtime.h>
#include <hip/hip_bf16.h>

#define BN 8
#define LN 4096
#define HN 2048
#define EN 512
#define KN 64
#define LT 32

typedef __attribute__((ext_vector_type(8))) short bf16x8;
typedef __attribute__((ext_vector_type(4))) float f32x4;

__device__ __forceinline__ short f2b(float x) {
  union { float f; unsigned u; } v; v.f = x;
  unsigned r = v.u + 0x7fffu + ((v.u >> 16) & 1u);  // RNE f32->bf16
  return (short)(r >> 16);
}

__device__ __forceinline__ void gload16(const void* g, void* s) {
  __builtin_amdgcn_global_load_lds(
      (const __attribute__((address_space(1))) unsigned int*)(unsigned long long)g,
      (__attribute__((address_space(3))) unsigned int*)(unsigned int)(unsigned long long)s,
      16, 0, 0);
}

// ---------- prep: elementwise f32 -> bf16 (optionally scaled) ----------
__global__ __launch_bounds__(256) void prep_cvt(const float* __restrict__ src,
                                                short* __restrict__ dst, float scale) {
  int i = blockIdx.x * 256 + threadIdx.x;
  f32x4 a = *(const f32x4*)(src + (size_t)i * 8);
  f32x4 b = *(const f32x4*)(src + (size_t)i * 8 + 4);
  bf16x8 r;
  r[0] = f2b(a[0] * scale); r[1] = f2b(a[1] * scale);
  r[2] = f2b(a[2] * scale); r[3] = f2b(a[3] * scale);
  r[4] = f2b(b[0] * scale); r[5] = f2b(b[1] * scale);
  r[6] = f2b(b[2] * scale); r[7] = f2b(b[3] * scale);
  *(bf16x8*)(dst + (size_t)i * 8) = r;
}

// ---------- prep: values [b][l][e] f32 -> valsT [b][e][l] bf16 ----------
__global__ __launch_bounds__(256) void prep_v(const float* __restrict__ vals,
                                              short* __restrict__ valsT) {
  __shared__ short tile[64 * 66];  // [l][e], stride 66
  const int b = blockIdx.z;
  const int l0 = blockIdx.x * 64, e0 = blockIdx.y * 64;
  const int tid = threadIdx.x;
  {
    int lr = tid >> 2, ec = (tid & 3) * 16;
    const float* src = vals + ((size_t)b * LN + l0 + lr) * EN + e0 + ec;
    short* trow = tile + lr * 66 + ec;
#pragma unroll
    for (int q = 0; q < 4; ++q) {
      f32x4 v = *(const f32x4*)(src + q * 4);
      unsigned u0 = (unsigned)(unsigned short)f2b(v[0]) | ((unsigned)(unsigned short)f2b(v[1]) << 16);
      unsigned u1 = (unsigned)(unsigned short)f2b(v[2]) | ((unsigned)(unsigned short)f2b(v[3]) << 16);
      *(unsigned*)(trow + q * 4) = u0;
      *(unsigned*)(trow + q * 4 + 2) = u1;
    }
  }
  __syncthreads();
  {
    int er = tid >> 2, lc = (tid & 3) * 16;
    union { short s[16]; bf16x8 v[2]; } u;
#pragma unroll
    for (int k2 = 0; k2 < 16; ++k2) u.s[k2] = tile[(lc + k2) * 66 + er];
    short* dst = valsT + ((size_t)b * EN + e0 + er) * LN + l0 + lc;
    *(bf16x8*)dst = u.v[0];
    *(bf16x8*)(dst + 8) = u.v[1];
  }
}

// ---------- stats: partial Z[hc][b][l] = sum over 512 h of 2^u ----------
__global__ __launch_bounds__(256) void k_stats2(const short* __restrict__ xb,
                                                const short* __restrict__ yb,
                                                float* __restrict__ ps) {
  const int b = blockIdx.y, hc = blockIdx.z;
  const int tid = threadIdx.x, w = tid >> 6, lane = tid & 63;
  const int row = lane & 15, g = lane >> 4;
  const int lb = blockIdx.x * 128 + w * 32;
  const size_t bL = (size_t)b * LN, bH = (size_t)b * HN;

  bf16x8 xa[2][2];
#pragma unroll
  for (int lt = 0; lt < 2; ++lt) {
    const short* xp = xb + ((bL + lb + lt * 16 + row) << 6) + 8 * g;
    xa[lt][0] = *(const bf16x8*)xp;
    xa[lt][1] = *(const bf16x8*)(xp + 32);
  }
  float s[2][4] = {{0.f, 0.f, 0.f, 0.f}, {0.f, 0.f, 0.f, 0.f}};
  const short* ybase = yb + ((bH + hc * 512 + row) << 6) + 8 * g;
#pragma unroll 2
  for (int it = 0; it < 32; ++it) {
    const short* yp = ybase + ((size_t)it << 10);
    bf16x8 y0 = *(const bf16x8*)yp;
    bf16x8 y1 = *(const bf16x8*)(yp + 32);
#pragma unroll
    for (int lt = 0; lt < 2; ++lt) {
      f32x4 a = {0.f, 0.f, 0.f, 0.f};
      a = __builtin_amdgcn_mfma_f32_16x16x32_bf16(xa[lt][0], y0, a, 0, 0, 0);
      a = __builtin_amdgcn_mfma_f32_16x16x32_bf16(xa[lt][1], y1, a, 0, 0, 0);
#pragma unroll
      for (int r = 0; r < 4; ++r) s[lt][r] += __builtin_amdgcn_exp2f(a[r]);
    }
  }
#pragma unroll
  for (int d = 1; d < 16; d <<= 1)
#pragma unroll
    for (int lt = 0; lt < 2; ++lt)
#pragma unroll
      for (int r = 0; r < 4; ++r) s[lt][r] += __shfl_xor(s[lt][r], d);
  if (row == 0) {
#pragma unroll
    for (int lt = 0; lt < 2; ++lt)
#pragma unroll
      for (int r = 0; r < 4; ++r)
        ps[(size_t)hc * (BN * LN) + bL + lb + lt * 16 + 4 * g + r] = s[lt][r];
  }
}

__global__ void k_comb(const float* __restrict__ ps, float* __restrict__ wv) {
  int idx = blockIdx.x * 256 + threadIdx.x;
  float z = ps[idx] + ps[BN * LN + idx] + ps[2 * BN * LN + idx] + ps[3 * BN * LN + idx];
  wv[idx] = 1.0f / z;
}

// ---------- main: out[b,h,e] = sum_l softmax_h * vals[l,e] ----------
// grid 1024 (XCD-chunked), 256 thr (4 waves). BH=64, BE=128, LT=32.
__global__ __launch_bounds__(256, 4) void k_main2(
    const short* __restrict__ valsT, const short* __restrict__ xb,
    const short* __restrict__ yb, const float* __restrict__ wv,
    float* __restrict__ out) {
  // LDS: vT 2x8192 @0 | xT 2x4096 @16384 | pT 2x4096 @24576 | sw 2x128 @32768
  __shared__ __align__(16) char smem[33024];
  const int tid = threadIdx.x;
  const int lane = tid & 63, w = tid >> 6;
  const int row = lane & 15, g = lane >> 4;

  int flat = blockIdx.x + 32 * blockIdx.y + 128 * blockIdx.z;
  int re = (flat & 7) * 128 + (flat >> 3);  // chunk per XCD: all h-blocks of (e,b) colocate
  const int hb = (re & 31) * 64;
  const int eb = ((re >> 5) & 3) * 128;
  const int b = re >> 7;
  const size_t bL = (size_t)b * LN, bH = (size_t)b * HN;

  // loop-invariant y B-frags for MFMA1: h rows (w>>1)*32 + j2*16 + row
  bf16x8 ya[2][2];
#pragma unroll
  for (int j2 = 0; j2 < 2; ++j2) {
    const short* yp = yb + ((bH + hb + ((w >> 1) * 2 + j2) * 16 + row) << 6) + 8 * g;
    ya[j2][0] = *(const bf16x8*)yp;
    ya[j2][1] = *(const bf16x8*)(yp + 32);
  }

  f32x4 acc[2][4];
#pragma unroll
  for (int at = 0; at < 2; ++at)
#pragma unroll
    for (int n = 0; n < 4; ++n) acc[at][n] = (f32x4){0.f, 0.f, 0.f, 0.f};

  const int wbase = __builtin_amdgcn_readfirstlane(tid & ~63);

  auto stage = [&](int buf, int l0n) {
#pragma unroll
    for (int j = 0; j < 2; ++j) {  // vT: [e 0..127][4 slots of 8 l], slot^=(e>>1)&3
      int i = j * 256 + tid;
      int e = i >> 2, sl = (i & 3) ^ ((e >> 1) & 3);
      const short* src = valsT + (((size_t)b * EN + eb + e) << 12) + l0n + 8 * sl;
      gload16(src, smem + buf * 8192 + (j * 256 + wbase) * 16);
    }
    {  // xT: [l 0..31][8 slots of 8 k], slot^=(l&7)
      int l = tid >> 3, sl = (tid & 7) ^ (l & 7);
      const short* src = xb + ((bL + l0n + l) << 6) + 8 * sl;
      gload16(src, smem + 16384 + buf * 4096 + wbase * 16);
    }
    if (tid < 8) {  // sw: 32 f32
      gload16(wv + bL + l0n + 4 * tid, smem + 32768 + buf * 128);
    }
  };

  stage(0, 0);
  __syncthreads();

  const int t = w & 1, hp = w >> 1;
  int cur = 0;
  for (int it = 0; it < LN / LT; ++it) {
    int l0 = it * LT;
    if (it + 1 < LN / LT) stage(cur ^ 1, l0 + LT);

    // ---- MFMA1: S-tile (l-tile t, h-tiles 2hp,2hp+1) -> P -> pT[cur] ----
    short* xT = (short*)(smem + 16384 + cur * 4096);
    char* pT = smem + 24576 + cur * 4096;
    float* sw = (float*)(smem + 32768 + cur * 128);

    int sp0 = g ^ (row & 7);
    const short* xrow = xT + ((t * 16 + row) << 6);
    bf16x8 xa0 = *(const bf16x8*)(xrow + (sp0 << 3));
    bf16x8 xa1 = *(const bf16x8*)(xrow + ((sp0 ^ 4) << 3));
    float swv[4];
#pragma unroll
    for (int r = 0; r < 4; ++r) swv[r] = sw[t * 16 + 4 * g + r];
#pragma unroll
    for (int j2 = 0; j2 < 2; ++j2) {
      f32x4 s4 = {0.f, 0.f, 0.f, 0.f};
      s4 = __builtin_amdgcn_mfma_f32_16x16x32_bf16(xa0, ya[j2][0], s4, 0, 0, 0);
      s4 = __builtin_amdgcn_mfma_f32_16x16x32_bf16(xa1, ya[j2][1], s4, 0, 0, 0);
      int hq = (hp * 2 + j2) * 16 + row;  // h' in [0,64)
      unsigned u0 = (unsigned)(unsigned short)f2b(__builtin_amdgcn_exp2f(s4[0]) * swv[0]) |
                    ((unsigned)(unsigned short)f2b(__builtin_amdgcn_exp2f(s4[1]) * swv[1]) << 16);
      unsigned u1 = (unsigned)(unsigned short)f2b(__builtin_amdgcn_exp2f(s4[2]) * swv[2]) |
                    ((unsigned)(unsigned short)f2b(__builtin_amdgcn_exp2f(s4[3]) * swv[3]) << 16);
      int sphy = (2 * t + (g >> 1)) ^ ((hq >> 1) & 3);
      *(unsigned long long*)(pT + hq * 64 + sphy * 16 + (g & 1) * 8) =
          (unsigned long long)u0 | ((unsigned long long)u1 << 32);
    }
    __syncthreads();

    // ---- MFMA2: acc += P^T x V ----
    char* vT = smem + cur * 8192;
    bf16x8 pa[2];
#pragma unroll
    for (int at = 0; at < 2; ++at) {
      int hq = (w >> 1) * 32 + at * 16 + row;
      pa[at] = *(const bf16x8*)(pT + hq * 64 + ((g ^ ((hq >> 1) & 3)) << 4));
    }
#pragma unroll
    for (int n = 0; n < 4; ++n) {
      int el = (w & 1) * 64 + n * 16 + row;
      bf16x8 vb = *(const bf16x8*)(vT + el * 64 + ((g ^ ((el >> 1) & 3)) << 4));
#pragma unroll
      for (int at = 0; at < 2; ++at)
        acc[at][n] = __builtin_amdgcn_mfma_f32_16x16x32_bf16(pa[at], vb, acc[at][n], 0, 0, 0);
    }
    __syncthreads();
    cur ^= 1;
  }

#pragma unroll
  for (int at = 0; at < 2; ++at)
#pragma unroll
    for (int n = 0; n < 4; ++n)
#pragma unroll
      for (int r = 0; r < 4; ++r) {
        int h = hb + (w >> 1) * 32 + at * 16 + 4 * g + r;
        int e = eb + (w & 1) * 64 + n * 16 + row;
        out[(bH + h) * (size_t)EN + e] = acc[at][n][r];
      }
}

// ================= fallback path (round-1 kernels, ws < 40.5 MB) =================
__device__ __forceinline__ bf16x8 cvt8(const float* __restrict__ p) {
  f32x4 a = *(const f32x4*)(p);
  f32x4 b = *(const f32x4*)(p + 4);
  bf16x8 r;
  r[0] = f2b(a[0]); r[1] = f2b(a[1]); r[2] = f2b(a[2]); r[3] = f2b(a[3]);
  r[4] = f2b(b[0]); r[5] = f2b(b[1]); r[6] = f2b(b[2]); r[7] = f2b(b[3]);
  return r;
}

__global__ __launch_bounds__(256) void k_stats_o(const float* __restrict__ xd,
                                                 const float* __restrict__ yd,
                                                 float* __restrict__ mz) {
  const int b = blockIdx.y;
  const int w = threadIdx.x >> 6;
  const int lane = threadIdx.x & 63;
  const int row = lane & 15, g = lane >> 4;
  const int lb = blockIdx.x * 64 + w * 16;
  const float* xp = xd + ((size_t)b * LN + lb + row) * KN + g * 8;
  bf16x8 a0 = cvt8(xp), a1 = cvt8(xp + 32);
  float m[4], s[4];
#pragma unroll
  for (int r = 0; r < 4; ++r) { m[r] = -1e30f; s[r] = 0.f; }
  const float* ybp = yd + ((size_t)b * HN + row) * KN + g * 8;
  for (int h0 = 0; h0 < HN; h0 += 16) {
    bf16x8 b0 = cvt8(ybp + (size_t)h0 * KN);
    bf16x8 b1 = cvt8(ybp + (size_t)h0 * KN + 32);
    f32x4 acc = {0.f, 0.f, 0.f, 0.f};
    acc = __builtin_amdgcn_mfma_f32_16x16x32_bf16(a0, b0, acc, 0, 0, 0);
    acc = __builtin_amdgcn_mfma_f32_16x16x32_bf16(a1, b1, acc, 0, 0, 0);
#pragma unroll
    for (int r = 0; r < 4; ++r) {
      float v = acc[r] * 0.125f;
      float mn = fmaxf(m[r], v);
      s[r] = s[r] * __expf(m[r] - mn) + __expf(v - mn);
      m[r] = mn;
    }
  }
#pragma unroll
  for (int d = 1; d < 16; d <<= 1) {
#pragma unroll
    for (int r = 0; r < 4; ++r) {
      float mo = __shfl_xor(m[r], d);
      float so = __shfl_xor(s[r], d);
      float mn = fmaxf(m[r], mo);
      s[r] = s[r] * __expf(m[r] - mn) + so * __expf(mo - mn);
      m[r] = mn;
    }
  }
  if (row == 0) {
#pragma unroll
    for (int r = 0; r < 4; ++r) {
      size_t idx = (size_t)b * LN + lb + 4 * g + r;
      mz[idx] = m[r];
      mz[(size_t)BN * LN + idx] = 1.0f / s[r];
    }
  }
}

__global__ __launch_bounds__(512) void k_main_o(const float* __restrict__ vals,
                                                const float* __restrict__ xd,
                                                const float* __restrict__ yd,
                                                const float* __restrict__ mz,
                                                float* __restrict__ out) {
  __shared__ short vT[256][34];
  __shared__ short pT[128][34];
  __shared__ short xT[LT][72];
  __shared__ float smm[LT], smz[LT];
  const int b = blockIdx.z;
  const int hb = blockIdx.x * 128;
  const int eb = blockIdx.y * 256;
  const int tid = threadIdx.x;
  const int w = tid >> 6, lane = tid & 63;
  const int row = lane & 15, g = lane >> 4;
  const float* yp = yd + ((size_t)b * HN + hb + w * 16 + row) * KN + g * 8;
  bf16x8 ya0 = cvt8(yp), ya1 = cvt8(yp + 32);
  f32x4 acc[16];
#pragma unroll
  for (int n = 0; n < 16; ++n) acc[n] = (f32x4){0.f, 0.f, 0.f, 0.f};
  const float* mzb = mz + (size_t)b * LN;
  const float* rzb = mz + (size_t)BN * LN + (size_t)b * LN;
  for (int l0 = 0; l0 < LN; l0 += LT) {
    __syncthreads();
    {
      int xl = tid >> 4, xk = (tid & 15) * 4;
      f32x4 xv = *(const f32x4*)(xd + ((size_t)b * LN + l0 + xl) * KN + xk);
      union { short h[4]; int i[2]; } u;
      u.h[0] = f2b(xv[0]); u.h[1] = f2b(xv[1]); u.h[2] = f2b(xv[2]); u.h[3] = f2b(xv[3]);
      int* dst = (int*)(&xT[xl][xk]);
      dst[0] = u.i[0]; dst[1] = u.i[1];
    }
#pragma unroll
    for (int lp = 0; lp < 4; ++lp) {
      int vl = (tid >> 6) + lp * 8;
      const float* vrow = vals + ((size_t)b * LN + l0 + vl) * EN + eb;
#pragma unroll
      for (int u2 = 0; u2 < 4; ++u2) {
        int e = (tid & 63) + u2 * 64;
        vT[e][vl] = f2b(vrow[e]);
      }
    }
    if (tid < LT) { smm[tid] = mzb[l0 + tid]; smz[tid] = rzb[l0 + tid]; }
    __syncthreads();
#pragma unroll
    for (int t2 = 0; t2 < 2; ++t2) {
      const short* xr = &xT[t2 * 16 + row][0];
      bf16x8 xb0 = *(const bf16x8*)(xr + 8 * g);
      bf16x8 xb1 = *(const bf16x8*)(xr + 32 + 8 * g);
      f32x4 sa = {0.f, 0.f, 0.f, 0.f};
      sa = __builtin_amdgcn_mfma_f32_16x16x32_bf16(ya0, xb0, sa, 0, 0, 0);
      sa = __builtin_amdgcn_mfma_f32_16x16x32_bf16(ya1, xb1, sa, 0, 0, 0);
      int lcol = t2 * 16 + row;
      float mm = smm[lcol], zz = smz[lcol];
#pragma unroll
      for (int r = 0; r < 4; ++r) {
        float p = __expf(sa[r] * 0.125f - mm) * zz;
        pT[w * 16 + 4 * g + r][lcol] = f2b(p);
      }
    }
    __syncthreads();
    bf16x8 pa;
    {
      const int* pi = (const int*)(&pT[w * 16 + row][0] + 8 * g);
      union { int i[4]; bf16x8 f; } u;
      u.i[0] = pi[0]; u.i[1] = pi[1]; u.i[2] = pi[2]; u.i[3] = pi[3];
      pa = u.f;
    }
#pragma unroll
    for (int n = 0; n < 16; ++n) {
      const int* vi = (const int*)(&vT[n * 16 + row][0] + 8 * g);
      union { int i[4]; bf16x8 f; } u;
      u.i[0] = vi[0]; u.i[1] = vi[1]; u.i[2] = vi[2]; u.i[3] = vi[3];
      acc[n] = __builtin_amdgcn_mfma_f32_16x16x32_bf16(pa, u.f, acc[n], 0, 0, 0);
    }
  }
#pragma unroll
  for (int n = 0; n < 16; ++n)
#pragma unroll
    for (int r = 0; r < 4; ++r) {
      int h = hb + w * 16 + 4 * g + r;
      int e = eb + n * 16 + row;
      out[((size_t)b * HN + h) * EN + e] = acc[n][r];
    }
}

extern "C" void kernel_launch(void* const* d_in, const int* in_sizes, int n_in,
                              void* d_out, int out_size, void* d_ws, size_t ws_size,
                              hipStream_t stream) {
  const float* vals = (const float*)d_in[2];
  const float* xd = (const float*)d_in[3];
  const float* yd = (const float*)d_in[4];
  float* out = (float*)d_out;

  if (ws_size >= 40501248ull) {
    char* wsb = (char*)d_ws;
    short* valsT = (short*)wsb;                       // 33554432 B
    short* xbuf  = (short*)(wsb + 33554432);          //  4194304 B
    short* ybuf  = (short*)(wsb + 37748736);          //  2097152 B
    float* ps    = (float*)(wsb + 39845888);          //   524288 B
    float* wv    = (float*)(wsb + 40370176);          //   131072 B

    const float c0 = 0.125f * 1.4426950408889634f;    // scale * log2(e)
    prep_cvt<<<dim3(BN * LN * KN / 2048), 256, 0, stream>>>(xd, xbuf, c0);
    prep_cvt<<<dim3(BN * HN * KN / 2048), 256, 0, stream>>>(yd, ybuf, 1.0f);
    prep_v<<<dim3(LN / 64, EN / 64, BN), 256, 0, stream>>>(vals, valsT);
    k_stats2<<<dim3(LN / 128, BN, 4), 256, 0, stream>>>(xbuf, ybuf, ps);
    k_comb<<<dim3(BN * LN / 256), 256, 0, stream>>>(ps, wv);
    k_main2<<<dim3(32, 4, 8), 256, 0, stream>>>(valsT, xbuf, ybuf, wv, out);
  } else {
    float* mz = (float*)d_ws;
    k_stats_o<<<dim3(LN / 64, BN), 256, 0, stream>>>(xd, yd, mz);
    k_main_o<<<dim3(HN / 128, EN / 256, BN), 512, 0, stream>>>(vals, xd, yd, mz, out);
  }
}

// Round 4
// 182.191 us; speedup vs baseline: 2.2041x; 1.0843x over previous
//
#include <hip/hip_runtime.h>
#include <hip/hip_bf16.h>

#define BN 8
#define LN 4096
#define HN 2048
#define EN 512
#define KN 64
#define LT 32
#define NIT 128

typedef __attribute__((ext_vector_type(8))) short bf16x8;
typedef __attribute__((ext_vector_type(4))) float f32x4;

__device__ __forceinline__ short f2b(float x) {
  union { float f; unsigned u; } v; v.f = x;
  unsigned r = v.u + 0x7fffu + ((v.u >> 16) & 1u);  // RNE f32->bf16
  return (short)(r >> 16);
}

__device__ __forceinline__ bf16x8 cvt8(const float* __restrict__ p) {
  f32x4 a = *(const f32x4*)(p);
  f32x4 b = *(const f32x4*)(p + 4);
  bf16x8 r;
  r[0] = f2b(a[0]); r[1] = f2b(a[1]); r[2] = f2b(a[2]); r[3] = f2b(a[3]);
  r[4] = f2b(b[0]); r[5] = f2b(b[1]); r[6] = f2b(b[2]); r[7] = f2b(b[3]);
  return r;
}

__device__ __forceinline__ void gload16(const void* g, void* s) {
  __builtin_amdgcn_global_load_lds(
      (const __attribute__((address_space(1))) unsigned int*)(unsigned long long)g,
      (__attribute__((address_space(3))) unsigned int*)(unsigned int)(unsigned long long)s,
      16, 0, 0);
}

// ---------- prep: x (scaled) and y f32 -> bf16, one launch ----------
__global__ __launch_bounds__(256) void prep_cvt2(const float* __restrict__ xs,
                                                 short* __restrict__ xo,
                                                 const float* __restrict__ ys,
                                                 short* __restrict__ yo) {
  int bx = blockIdx.x;
  const float* src;
  short* dst;
  float scale;
  int i;
  if (bx < 1024) {  // x: 2,097,152 elems
    i = bx * 256 + threadIdx.x;
    src = xs; dst = xo; scale = 0.125f * 1.4426950408889634f;
  } else {          // y: 1,048,576 elems
    i = (bx - 1024) * 256 + threadIdx.x;
    src = ys; dst = yo; scale = 1.0f;
  }
  f32x4 a = *(const f32x4*)(src + (size_t)i * 8);
  f32x4 b = *(const f32x4*)(src + (size_t)i * 8 + 4);
  bf16x8 r;
  r[0] = f2b(a[0] * scale); r[1] = f2b(a[1] * scale);
  r[2] = f2b(a[2] * scale); r[3] = f2b(a[3] * scale);
  r[4] = f2b(b[0] * scale); r[5] = f2b(b[1] * scale);
  r[6] = f2b(b[2] * scale); r[7] = f2b(b[3] * scale);
  *(bf16x8*)(dst + (size_t)i * 8) = r;
}

// ---------- merged: prep_v (blocks 0..4095) || stats (blocks 4096..5119) ----------
__global__ __launch_bounds__(256) void k_pv_stats(const float* __restrict__ vals,
                                                  short* __restrict__ valsT,
                                                  const short* __restrict__ xb,
                                                  const short* __restrict__ yb,
                                                  float* __restrict__ ps) {
  __shared__ short tile[64 * 66];
  const int bx = blockIdx.x;
  const int tid = threadIdx.x;
  if (bx < 4096) {
    // ---- values [b][l][e] f32 -> valsT [b][e][l] bf16 ----
    const int b = bx >> 9;
    const int e0 = ((bx >> 6) & 7) * 64;
    const int l0 = (bx & 63) * 64;
    {
      int lr = tid >> 2, ec = (tid & 3) * 16;
      const float* src = vals + ((size_t)b * LN + l0 + lr) * EN + e0 + ec;
      short* trow = tile + lr * 66 + ec;
#pragma unroll
      for (int q = 0; q < 4; ++q) {
        f32x4 v = *(const f32x4*)(src + q * 4);
        unsigned u0 = (unsigned)(unsigned short)f2b(v[0]) | ((unsigned)(unsigned short)f2b(v[1]) << 16);
        unsigned u1 = (unsigned)(unsigned short)f2b(v[2]) | ((unsigned)(unsigned short)f2b(v[3]) << 16);
        *(unsigned*)(trow + q * 4) = u0;
        *(unsigned*)(trow + q * 4 + 2) = u1;
      }
    }
    __syncthreads();
    {
      int er = tid >> 2, lc = (tid & 3) * 16;
      union { short s[16]; bf16x8 v[2]; } u;
#pragma unroll
      for (int k2 = 0; k2 < 16; ++k2) u.s[k2] = tile[(lc + k2) * 66 + er];
      short* dst = valsT + ((size_t)b * EN + e0 + er) * LN + l0 + lc;
      *(bf16x8*)dst = u.v[0];
      *(bf16x8*)(dst + 8) = u.v[1];
    }
  } else {
    // ---- stats: ps[hc][b][l] = sum over 512 h of 2^u ----
    const int idx = bx - 4096;
    const int b = (idx >> 5) & 7, hc = idx >> 8;
    const int w = tid >> 6, lane = tid & 63;
    const int row = lane & 15, g = lane >> 4;
    const int lb = (idx & 31) * 128 + w * 32;
    const size_t bL = (size_t)b * LN, bH = (size_t)b * HN;
    bf16x8 xa[2][2];
#pragma unroll
    for (int lt = 0; lt < 2; ++lt) {
      const short* xp = xb + ((bL + lb + lt * 16 + row) << 6) + 8 * g;
      xa[lt][0] = *(const bf16x8*)xp;
      xa[lt][1] = *(const bf16x8*)(xp + 32);
    }
    float s[2][4] = {{0.f, 0.f, 0.f, 0.f}, {0.f, 0.f, 0.f, 0.f}};
    const short* ybase = yb + ((bH + hc * 512 + row) << 6) + 8 * g;
#pragma unroll 2
    for (int it = 0; it < 32; ++it) {
      const short* yp = ybase + ((size_t)it << 10);
      bf16x8 y0 = *(const bf16x8*)yp;
      bf16x8 y1 = *(const bf16x8*)(yp + 32);
#pragma unroll
      for (int lt = 0; lt < 2; ++lt) {
        f32x4 a = {0.f, 0.f, 0.f, 0.f};
        a = __builtin_amdgcn_mfma_f32_16x16x32_bf16(xa[lt][0], y0, a, 0, 0, 0);
        a = __builtin_amdgcn_mfma_f32_16x16x32_bf16(xa[lt][1], y1, a, 0, 0, 0);
#pragma unroll
        for (int r = 0; r < 4; ++r) s[lt][r] += __builtin_amdgcn_exp2f(a[r]);
      }
    }
#pragma unroll
    for (int d = 1; d < 16; d <<= 1)
#pragma unroll
      for (int lt = 0; lt < 2; ++lt)
#pragma unroll
        for (int r = 0; r < 4; ++r) s[lt][r] += __shfl_xor(s[lt][r], d);
    if (row == 0) {
#pragma unroll
      for (int lt = 0; lt < 2; ++lt)
#pragma unroll
        for (int r = 0; r < 4; ++r)
          ps[(size_t)hc * (BN * LN) + bL + lb + lt * 16 + 4 * g + r] = s[lt][r];
    }
  }
}

__global__ void k_comb(const float* __restrict__ ps, float* __restrict__ wv) {
  int idx = blockIdx.x * 256 + threadIdx.x;
  float z = ps[idx] + ps[BN * LN + idx] + ps[2 * BN * LN + idx] + ps[3 * BN * LN + idx];
  wv[idx] = 1.0f / z;
}

// ---------- main v3: BH=64, BE=256, 8 waves, triple-buffer + counted vmcnt ----------
// LDS map: vT[3]@0 (16384 ea) | xT[3]@49152 (4096 ea) | pT@61440 (4096) | sw[3]@65536 (128 ea)
__global__ __launch_bounds__(512, 4) void k_main3(
    const short* __restrict__ valsT, const short* __restrict__ xb,
    const short* __restrict__ yb, const float* __restrict__ wv,
    float* __restrict__ out) {
  __shared__ __align__(16) char smem[65920];
  const int tid = threadIdx.x;
  const int w = tid >> 6, lane = tid & 63;
  const int row = lane & 15, g = lane >> 4;

  const int f = blockIdx.x;
  const int b = f & 7;                 // XCD f%8 <- batch b: valsT[b] (4MB) fits XCD L2
  const int rest = f >> 3;             // 0..63
  const int hb = (rest & 31) * 64;
  const int eb = (rest >> 5) * 256;
  const size_t bL = (size_t)b * LN, bH = (size_t)b * HN;

  const int wbase = __builtin_amdgcn_readfirstlane(tid & ~63);  // w*64

  // ---- invariant staging source pointers ----
  const short* vsrc[2];
#pragma unroll
  for (int j = 0; j < 2; ++j) {
    int i = j * 512 + tid;
    int e = i >> 2, sl = (i & 3) ^ ((e >> 1) & 3);
    vsrc[j] = valsT + (((size_t)b * EN + eb + e) << 12) + 8 * sl;
  }
  const short* xsrc;
  {
    int p = w * 32 + (lane & 31);
    int l = p >> 3, sl = (p & 7) ^ (l & 7);
    xsrc = xb + ((bL + l) << 6) + 8 * sl;
  }
  const float* ssrc = wv + bL + 4 * tid;  // used when tid<8

  auto stage = [&](int buf, int tl) {
    int loff = tl * 32;  // l advance in elements for l-fastest buffers
#pragma unroll
    for (int j = 0; j < 2; ++j)
      gload16(vsrc[j] + loff, smem + buf * 16384 + (j * 8192 + wbase * 16));
    if (lane < 32)
      gload16(xsrc + loff * 64, smem + 49152 + buf * 4096 + wbase * 8);  // x rows: 64 elems each
    if (tid < 8)
      gload16(ssrc + loff, smem + 65536 + buf * 128);
  };

  // ---- MFMA1 role: wave w -> h-tile ht, l-tile lt ----
  const int ht = w >> 1, lt = w & 1;
  bf16x8 ya0, ya1;
  {
    const short* yp = yb + ((bH + hb + ht * 16 + row) << 6) + 8 * g;
    ya0 = *(const bf16x8*)yp;
    ya1 = *(const bf16x8*)(yp + 32);
  }
  const int sp0 = g ^ (row & 7);
  const int xoffA = ((lt * 16 + row) << 7) + (sp0 << 4);
  const int xoffB = ((lt * 16 + row) << 7) + ((sp0 ^ 4) << 4);
  const int swoff = (lt * 16 + 4 * g) * 4;
  const int hq1 = ht * 16 + row;
  const int poff_w = hq1 * 64 + (((2 * lt + (g >> 1)) ^ ((hq1 >> 1) & 3)) << 4) + (g & 1) * 8;
  // ---- MFMA2 role: wave w -> h-half (w>>2), e-quarter (w&3) ----
  const int hq2a = (w >> 2) * 32 + row, hq2b = hq2a + 16;
  const int paoffA = hq2a * 64 + ((g ^ ((hq2a >> 1) & 3)) << 4);
  const int paoffB = hq2b * 64 + ((g ^ ((hq2b >> 1) & 3)) << 4);
  int vboff[4];
#pragma unroll
  for (int n = 0; n < 4; ++n) {
    int el = (w & 3) * 64 + n * 16 + row;
    vboff[n] = el * 64 + ((g ^ ((el >> 1) & 3)) << 4);
  }

  f32x4 acc[2][4];
#pragma unroll
  for (int at = 0; at < 2; ++at)
#pragma unroll
    for (int n = 0; n < 4; ++n) acc[at][n] = (f32x4){0.f, 0.f, 0.f, 0.f};

  // ---- prologue: stage tiles 0,1; wait tile0 (leave tile1 in flight) ----
  stage(0, 0);
  stage(1, 1);
  asm volatile("s_waitcnt vmcnt(3)" ::: "memory");
  __builtin_amdgcn_s_barrier();
  asm volatile("" ::: "memory");

  int rb = 0, sb = 2;
  for (int it = 0; it < NIT; ++it) {
    if (it + 2 < NIT) stage(sb, it + 2);

    // ---- MFMA1: S-tile -> P -> pT ----
    {
      const char* xbuf = smem + 49152 + rb * 4096;
      bf16x8 xa0 = *(const bf16x8*)(xbuf + xoffA);
      bf16x8 xa1 = *(const bf16x8*)(xbuf + xoffB);
      f32x4 sws = *(const f32x4*)(smem + 65536 + rb * 128 + swoff);
      f32x4 s4 = {0.f, 0.f, 0.f, 0.f};
      s4 = __builtin_amdgcn_mfma_f32_16x16x32_bf16(xa0, ya0, s4, 0, 0, 0);
      s4 = __builtin_amdgcn_mfma_f32_16x16x32_bf16(xa1, ya1, s4, 0, 0, 0);
      unsigned u0 = (unsigned)(unsigned short)f2b(__builtin_amdgcn_exp2f(s4[0]) * sws[0]) |
                    ((unsigned)(unsigned short)f2b(__builtin_amdgcn_exp2f(s4[1]) * sws[1]) << 16);
      unsigned u1 = (unsigned)(unsigned short)f2b(__builtin_amdgcn_exp2f(s4[2]) * sws[2]) |
                    ((unsigned)(unsigned short)f2b(__builtin_amdgcn_exp2f(s4[3]) * sws[3]) << 16);
      *(unsigned long long*)(smem + 61440 + poff_w) =
          (unsigned long long)u0 | ((unsigned long long)u1 << 32);
    }
    // mid barrier: LDS handoff only — staged loads stay in flight
    asm volatile("s_waitcnt lgkmcnt(0)" ::: "memory");
    __builtin_amdgcn_s_barrier();
    asm volatile("" ::: "memory");

    // ---- MFMA2: acc += P^T x V ----
    {
      const char* vbuf = smem + rb * 16384;
      bf16x8 pa0 = *(const bf16x8*)(smem + 61440 + paoffA);
      bf16x8 pa1 = *(const bf16x8*)(smem + 61440 + paoffB);
#pragma unroll
      for (int n = 0; n < 4; ++n) {
        bf16x8 vb = *(const bf16x8*)(vbuf + vboff[n]);
        acc[0][n] = __builtin_amdgcn_mfma_f32_16x16x32_bf16(pa0, vb, acc[0][n], 0, 0, 0);
        acc[1][n] = __builtin_amdgcn_mfma_f32_16x16x32_bf16(pa1, vb, acc[1][n], 0, 0, 0);
      }
    }
    // end barrier: counted — drain tile it+1, leave tile it+2 flying
    if (it < NIT - 2)
      asm volatile("s_waitcnt vmcnt(3) lgkmcnt(0)" ::: "memory");
    else
      asm volatile("s_waitcnt vmcnt(0) lgkmcnt(0)" ::: "memory");
    __builtin_amdgcn_s_barrier();
    asm volatile("" ::: "memory");

    rb = rb == 2 ? 0 : rb + 1;
    sb = sb == 2 ? 0 : sb + 1;
  }

#pragma unroll
  for (int at = 0; at < 2; ++at)
#pragma unroll
    for (int n = 0; n < 4; ++n)
#pragma unroll
      for (int r = 0; r < 4; ++r) {
        int h = hb + (w >> 2) * 32 + at * 16 + 4 * g + r;
        int e = eb + (w & 3) * 64 + n * 16 + row;
        out[(bH + h) * (size_t)EN + e] = acc[at][n][r];
      }
}

// ================= fallback path (round-1 kernels, ws < 40.5 MB) =================
__global__ __launch_bounds__(256) void k_stats_o(const float* __restrict__ xd,
                                                 const float* __restrict__ yd,
                                                 float* __restrict__ mz) {
  const int b = blockIdx.y;
  const int w = threadIdx.x >> 6;
  const int lane = threadIdx.x & 63;
  const int row = lane & 15, g = lane >> 4;
  const int lb = blockIdx.x * 64 + w * 16;
  const float* xp = xd + ((size_t)b * LN + lb + row) * KN + g * 8;
  bf16x8 a0 = cvt8(xp), a1 = cvt8(xp + 32);
  float m[4], s[4];
#pragma unroll
  for (int r = 0; r < 4; ++r) { m[r] = -1e30f; s[r] = 0.f; }
  const float* ybp = yd + ((size_t)b * HN + row) * KN + g * 8;
  for (int h0 = 0; h0 < HN; h0 += 16) {
    bf16x8 b0 = cvt8(ybp + (size_t)h0 * KN);
    bf16x8 b1 = cvt8(ybp + (size_t)h0 * KN + 32);
    f32x4 acc = {0.f, 0.f, 0.f, 0.f};
    acc = __builtin_amdgcn_mfma_f32_16x16x32_bf16(a0, b0, acc, 0, 0, 0);
    acc = __builtin_amdgcn_mfma_f32_16x16x32_bf16(a1, b1, acc, 0, 0, 0);
#pragma unroll
    for (int r = 0; r < 4; ++r) {
      float v = acc[r] * 0.125f;
      float mn = fmaxf(m[r], v);
      s[r] = s[r] * __expf(m[r] - mn) + __expf(v - mn);
      m[r] = mn;
    }
  }
#pragma unroll
  for (int d = 1; d < 16; d <<= 1) {
#pragma unroll
    for (int r = 0; r < 4; ++r) {
      float mo = __shfl_xor(m[r], d);
      float so = __shfl_xor(s[r], d);
      float mn = fmaxf(m[r], mo);
      s[r] = s[r] * __expf(m[r] - mn) + so * __expf(mo - mn);
      m[r] = mn;
    }
  }
  if (row == 0) {
#pragma unroll
    for (int r = 0; r < 4; ++r) {
      size_t idx = (size_t)b * LN + lb + 4 * g + r;
      mz[idx] = m[r];
      mz[(size_t)BN * LN + idx] = 1.0f / s[r];
    }
  }
}

__global__ __launch_bounds__(512) void k_main_o(const float* __restrict__ vals,
                                                const float* __restrict__ xd,
                                                const float* __restrict__ yd,
                                                const float* __restrict__ mz,
                                                float* __restrict__ out) {
  __shared__ short vT[256][34];
  __shared__ short pT[128][34];
  __shared__ short xT[LT][72];
  __shared__ float smm[LT], smz[LT];
  const int b = blockIdx.z;
  const int hb = blockIdx.x * 128;
  const int eb = blockIdx.y * 256;
  const int tid = threadIdx.x;
  const int w = tid >> 6, lane = tid & 63;
  const int row = lane & 15, g = lane >> 4;
  const float* yp = yd + ((size_t)b * HN + hb + w * 16 + row) * KN + g * 8;
  bf16x8 ya0 = cvt8(yp), ya1 = cvt8(yp + 32);
  f32x4 acc[16];
#pragma unroll
  for (int n = 0; n < 16; ++n) acc[n] = (f32x4){0.f, 0.f, 0.f, 0.f};
  const float* mzb = mz + (size_t)b * LN;
  const float* rzb = mz + (size_t)BN * LN + (size_t)b * LN;
  for (int l0 = 0; l0 < LN; l0 += LT) {
    __syncthreads();
    {
      int xl = tid >> 4, xk = (tid & 15) * 4;
      f32x4 xv = *(const f32x4*)(xd + ((size_t)b * LN + l0 + xl) * KN + xk);
      union { short h[4]; int i[2]; } u;
      u.h[0] = f2b(xv[0]); u.h[1] = f2b(xv[1]); u.h[2] = f2b(xv[2]); u.h[3] = f2b(xv[3]);
      int* dst = (int*)(&xT[xl][xk]);
      dst[0] = u.i[0]; dst[1] = u.i[1];
    }
#pragma unroll
    for (int lp = 0; lp < 4; ++lp) {
      int vl = (tid >> 6) + lp * 8;
      const float* vrow = vals + ((size_t)b * LN + l0 + vl) * EN + eb;
#pragma unroll
      for (int u2 = 0; u2 < 4; ++u2) {
        int e = (tid & 63) + u2 * 64;
        vT[e][vl] = f2b(vrow[e]);
      }
    }
    if (tid < LT) { smm[tid] = mzb[l0 + tid]; smz[tid] = rzb[l0 + tid]; }
    __syncthreads();
#pragma unroll
    for (int t2 = 0; t2 < 2; ++t2) {
      const short* xr = &xT[t2 * 16 + row][0];
      bf16x8 xb0 = *(const bf16x8*)(xr + 8 * g);
      bf16x8 xb1 = *(const bf16x8*)(xr + 32 + 8 * g);
      f32x4 sa = {0.f, 0.f, 0.f, 0.f};
      sa = __builtin_amdgcn_mfma_f32_16x16x32_bf16(ya0, xb0, sa, 0, 0, 0);
      sa = __builtin_amdgcn_mfma_f32_16x16x32_bf16(ya1, xb1, sa, 0, 0, 0);
      int lcol = t2 * 16 + row;
      float mm = smm[lcol], zz = smz[lcol];
#pragma unroll
      for (int r = 0; r < 4; ++r) {
        float p = __expf(sa[r] * 0.125f - mm) * zz;
        pT[w * 16 + 4 * g + r][lcol] = f2b(p);
      }
    }
    __syncthreads();
    bf16x8 pa;
    {
      const int* pi = (const int*)(&pT[w * 16 + row][0] + 8 * g);
      union { int i[4]; bf16x8 f; } u;
      u.i[0] = pi[0]; u.i[1] = pi[1]; u.i[2] = pi[2]; u.i[3] = pi[3];
      pa = u.f;
    }
#pragma unroll
    for (int n = 0; n < 16; ++n) {
      const int* vi = (const int*)(&vT[n * 16 + row][0] + 8 * g);
      union { int i[4]; bf16x8 f; } u;
      u.i[0] = vi[0]; u.i[1] = vi[1]; u.i[2] = vi[2]; u.i[3] = vi[3];
      acc[n] = __builtin_amdgcn_mfma_f32_16x16x32_bf16(pa, u.f, acc[n], 0, 0, 0);
    }
  }
#pragma unroll
  for (int n = 0; n < 16; ++n)
#pragma unroll
    for (int r = 0; r < 4; ++r) {
      int h = hb + w * 16 + 4 * g + r;
      int e = eb + n * 16 + row;
      out[((size_t)b * HN + h) * EN + e] = acc[n][r];
    }
}

extern "C" void kernel_launch(void* const* d_in, const int* in_sizes, int n_in,
                              void* d_out, int out_size, void* d_ws, size_t ws_size,
                              hipStream_t stream) {
  const float* vals = (const float*)d_in[2];
  const float* xd = (const float*)d_in[3];
  const float* yd = (const float*)d_in[4];
  float* out = (float*)d_out;

  if (ws_size >= 40501248ull) {
    char* wsb = (char*)d_ws;
    short* valsT = (short*)wsb;                       // 33554432 B
    short* xbuf  = (short*)(wsb + 33554432);          //  4194304 B
    short* ybuf  = (short*)(wsb + 37748736);          //  2097152 B
    float* ps    = (float*)(wsb + 39845888);          //   524288 B
    float* wv    = (float*)(wsb + 40370176);          //   131072 B

    prep_cvt2<<<dim3(1536), 256, 0, stream>>>(xd, xbuf, yd, ybuf);
    k_pv_stats<<<dim3(5120), 256, 0, stream>>>(vals, valsT, xbuf, ybuf, ps);
    k_comb<<<dim3(BN * LN / 256), 256, 0, stream>>>(ps, wv);
    k_main3<<<dim3(512), 512, 0, stream>>>(valsT, xbuf, ybuf, wv, out);
  } else {
    float* mz = (float*)d_ws;
    k_stats_o<<<dim3(LN / 64, BN), 256, 0, stream>>>(xd, yd, mz);
    k_main_o<<<dim3(HN / 128, EN / 256, BN), 512, 0, stream>>>(vals, xd, yd, mz, out);
  }
}

// Round 5
// 171.689 us; speedup vs baseline: 2.3389x; 1.0612x over previous
//
#include <hip/hip_runtime.h>
#include <hip/hip_bf16.h>

#define BN 8
#define LN 4096
#define HN 2048
#define EN 512
#define KN 64
#define LT 32
#define NIT 128

typedef __attribute__((ext_vector_type(8))) short bf16x8;
typedef __attribute__((ext_vector_type(4))) float f32x4;
typedef __attribute__((ext_vector_type(4))) unsigned u32x4;

__device__ __forceinline__ short f2b(float x) {
  union { float f; unsigned u; } v; v.f = x;
  unsigned r = v.u + 0x7fffu + ((v.u >> 16) & 1u);  // RNE f32->bf16
  return (short)(r >> 16);
}

__device__ __forceinline__ bf16x8 cvt8(const float* __restrict__ p) {
  f32x4 a = *(const f32x4*)(p);
  f32x4 b = *(const f32x4*)(p + 4);
  bf16x8 r;
  r[0] = f2b(a[0]); r[1] = f2b(a[1]); r[2] = f2b(a[2]); r[3] = f2b(a[3]);
  r[4] = f2b(b[0]); r[5] = f2b(b[1]); r[6] = f2b(b[2]); r[7] = f2b(b[3]);
  return r;
}

__device__ __forceinline__ void gload16(const void* g, void* s) {
  __builtin_amdgcn_global_load_lds(
      (const __attribute__((address_space(1))) unsigned int*)(unsigned long long)g,
      (__attribute__((address_space(3))) unsigned int*)(unsigned int)(unsigned long long)s,
      16, 0, 0);
}

// ---------- prep: x (scaled) and y f32 -> bf16, one launch ----------
__global__ __launch_bounds__(256) void prep_cvt2(const float* __restrict__ xs,
                                                 short* __restrict__ xo,
                                                 const float* __restrict__ ys,
                                                 short* __restrict__ yo) {
  int bx = blockIdx.x;
  const float* src;
  short* dst;
  float scale;
  int i;
  if (bx < 1024) {  // x: 2,097,152 elems
    i = bx * 256 + threadIdx.x;
    src = xs; dst = xo; scale = 0.125f * 1.4426950408889634f;
  } else {          // y: 1,048,576 elems
    i = (bx - 1024) * 256 + threadIdx.x;
    src = ys; dst = yo; scale = 1.0f;
  }
  f32x4 a = *(const f32x4*)(src + (size_t)i * 8);
  f32x4 b = *(const f32x4*)(src + (size_t)i * 8 + 4);
  bf16x8 r;
  r[0] = f2b(a[0] * scale); r[1] = f2b(a[1] * scale);
  r[2] = f2b(a[2] * scale); r[3] = f2b(a[3] * scale);
  r[4] = f2b(b[0] * scale); r[5] = f2b(b[1] * scale);
  r[6] = f2b(b[2] * scale); r[7] = f2b(b[3] * scale);
  *(bf16x8*)(dst + (size_t)i * 8) = r;
}

// ---------- merged: prep_v (blocks 0..4095) || stats (blocks 4096..5119) ----------
__global__ __launch_bounds__(256) void k_pv_stats(const float* __restrict__ vals,
                                                  short* __restrict__ valsT,
                                                  const short* __restrict__ xb,
                                                  const short* __restrict__ yb,
                                                  float* __restrict__ ps) {
  __shared__ unsigned trT[2048];  // 64 e-rows x 32 l-pair dwords, XOR-swizzled
  const int bx = blockIdx.x;
  const int tid = threadIdx.x;
  if (bx < 4096) {
    // ---- values [b][l][e] f32 -> valsT [b][e][l] bf16 (64l x 64e tile) ----
    const int b = bx >> 9;
    const int e0 = ((bx >> 6) & 7) * 64;
    const int l0 = (bx & 63) * 64;
    {
      int lr2 = tid >> 3;           // 0..31 -> rows 2lr2, 2lr2+1
      int ec = (tid & 7) * 8;
      const float* r0 = vals + ((size_t)b * LN + l0 + 2 * lr2) * EN + e0 + ec;
      const float* r1 = r0 + EN;
      f32x4 a0 = *(const f32x4*)r0, a1 = *(const f32x4*)(r0 + 4);
      f32x4 c0 = *(const f32x4*)r1, c1 = *(const f32x4*)(r1 + 4);
#pragma unroll
      for (int j = 0; j < 8; ++j) {
        float lo = (j < 4) ? a0[j] : a1[j - 4];
        float hi = (j < 4) ? c0[j] : c1[j - 4];
        unsigned dw = (unsigned)(unsigned short)f2b(lo) |
                      ((unsigned)(unsigned short)f2b(hi) << 16);
        int e = ec + j;
        int sz = (((e >> 3) ^ e) & 7) << 2;
        trT[e * 32 + (lr2 ^ sz)] = dw;
      }
    }
    __syncthreads();
    {
      int er = tid >> 2, lq = (tid & 3) * 8;  // lq in {0,8,16,24} -> l = 2lq..2lq+15
      int sr = ((er >> 3) ^ er) & 7;
      const unsigned* base = trT + er * 32;
      u32x4 u0 = *(const u32x4*)(base + ((((lq >> 2) + 0) ^ sr) << 2));
      u32x4 u1 = *(const u32x4*)(base + ((((lq >> 2) + 1) ^ sr) << 2));
      short* dst = valsT + ((size_t)b * EN + e0 + er) * LN + l0 + 2 * lq;
      *(u32x4*)dst = u0;
      *(u32x4*)(dst + 8) = u1;
    }
  } else {
    // ---- stats: ps[hc][b][l] = sum over 512 h of 2^u ----
    const int idx = bx - 4096;
    const int b = (idx >> 5) & 7, hc = idx >> 8;
    const int w = tid >> 6, lane = tid & 63;
    const int row = lane & 15, g = lane >> 4;
    const int lb = (idx & 31) * 128 + w * 32;
    const size_t bL = (size_t)b * LN, bH = (size_t)b * HN;
    bf16x8 xa[2][2];
#pragma unroll
    for (int lt = 0; lt < 2; ++lt) {
      const short* xp = xb + ((bL + lb + lt * 16 + row) << 6) + 8 * g;
      xa[lt][0] = *(const bf16x8*)xp;
      xa[lt][1] = *(const bf16x8*)(xp + 32);
    }
    float s[2][4] = {{0.f, 0.f, 0.f, 0.f}, {0.f, 0.f, 0.f, 0.f}};
    const short* ybase = yb + ((bH + hc * 512 + row) << 6) + 8 * g;
#pragma unroll 2
    for (int it = 0; it < 32; ++it) {
      const short* yp = ybase + ((size_t)it << 10);
      bf16x8 y0 = *(const bf16x8*)yp;
      bf16x8 y1 = *(const bf16x8*)(yp + 32);
#pragma unroll
      for (int lt = 0; lt < 2; ++lt) {
        f32x4 a = {0.f, 0.f, 0.f, 0.f};
        a = __builtin_amdgcn_mfma_f32_16x16x32_bf16(xa[lt][0], y0, a, 0, 0, 0);
        a = __builtin_amdgcn_mfma_f32_16x16x32_bf16(xa[lt][1], y1, a, 0, 0, 0);
#pragma unroll
        for (int r = 0; r < 4; ++r) s[lt][r] += __builtin_amdgcn_exp2f(a[r]);
      }
    }
#pragma unroll
    for (int d = 1; d < 16; d <<= 1)
#pragma unroll
      for (int lt = 0; lt < 2; ++lt)
#pragma unroll
        for (int r = 0; r < 4; ++r) s[lt][r] += __shfl_xor(s[lt][r], d);
    if (row == 0) {
#pragma unroll
      for (int lt = 0; lt < 2; ++lt)
#pragma unroll
        for (int r = 0; r < 4; ++r)
          ps[(size_t)hc * (BN * LN) + bL + lb + lt * 16 + 4 * g + r] = s[lt][r];
    }
  }
}

__global__ void k_comb(const float* __restrict__ ps, float* __restrict__ wv) {
  int idx = blockIdx.x * 256 + threadIdx.x;
  float z = ps[idx] + ps[BN * LN + idx] + ps[2 * BN * LN + idx] + ps[3 * BN * LN + idx];
  wv[idx] = 1.0f / z;
}

// ---------- main v4: P-pipelined, ONE barrier/iter, counted vmcnt ----------
// LDS: vT[3]x16384 @0 | xT[3]x4096 @49152 | pT[2]x4096 @61440 | sw[3]x128 @69632
__global__ __launch_bounds__(512, 4) void k_main4(
    const short* __restrict__ valsT, const short* __restrict__ xb,
    const short* __restrict__ yb, const float* __restrict__ wv,
    float* __restrict__ out) {
  __shared__ __align__(16) char smem[70016];
  const int tid = threadIdx.x;
  const int w = tid >> 6, lane = tid & 63;
  const int row = lane & 15, g = lane >> 4;

  const int f = blockIdx.x;
  const int b = f & 7;                 // XCD f%8 <- batch b (valsT[b] 4MB per XCD L2)
  const int rest = f >> 3;
  const int hb = (rest & 31) * 64;
  const int eb = (rest >> 5) * 256;
  const size_t bL = (size_t)b * LN, bH = (size_t)b * HN;

  const int wbase = __builtin_amdgcn_readfirstlane(tid & ~63);  // w*64

  // ---- staging source pointers ----
  const short* vsrc[2];
#pragma unroll
  for (int j = 0; j < 2; ++j) {
    int i = j * 512 + tid;
    int e = i >> 2, sl = (i & 3) ^ ((e >> 1) & 3);
    vsrc[j] = valsT + (((size_t)b * EN + eb + e) << 12) + 8 * sl;
  }
  const short* xsrc;
  {
    int p = w * 32 + (lane & 31);
    int l = p >> 3, sl = (p & 7) ^ (l & 7);
    xsrc = xb + ((bL + l) << 6) + 8 * sl;
  }
  const float* ssrc = wv + bL + 4 * tid;  // used when tid<8

  // ORDER: xT + sw first, vT last -> uniform vmcnt(2) keeps only newest vT pair
  auto stage = [&](int buf, int tl) {
    int loff = tl * 32;
    if (lane < 32)
      gload16(xsrc + loff * 64, smem + 49152 + buf * 4096 + wbase * 8);
    if (tid < 8)
      gload16(ssrc + loff, smem + 69632 + buf * 128);
#pragma unroll
    for (int j = 0; j < 2; ++j)
      gload16(vsrc[j] + loff, smem + buf * 16384 + (j * 8192 + wbase * 16));
  };

  // ---- MFMA1 role: wave w -> h-tile ht, l-tile lt ----
  const int ht = w >> 1, lt = w & 1;
  bf16x8 ya0, ya1;
  {
    const short* yp = yb + ((bH + hb + ht * 16 + row) << 6) + 8 * g;
    ya0 = *(const bf16x8*)yp;
    ya1 = *(const bf16x8*)(yp + 32);
  }
  const int sp0 = g ^ (row & 7);
  const int xoffA = ((lt * 16 + row) << 7) + (sp0 << 4);
  const int xoffB = ((lt * 16 + row) << 7) + ((sp0 ^ 4) << 4);
  const int swoff = (lt * 16 + 4 * g) * 4;
  const int hq1 = ht * 16 + row;
  const int poff_w = hq1 * 64 + (((2 * lt + (g >> 1)) ^ ((hq1 >> 1) & 3)) << 4) + (g & 1) * 8;
  // ---- MFMA2 role: wave w -> h-half (w>>2), e-quarter (w&3) ----
  const int hq2a = (w >> 2) * 32 + row, hq2b = hq2a + 16;
  const int paoffA = hq2a * 64 + ((g ^ ((hq2a >> 1) & 3)) << 4);
  const int paoffB = hq2b * 64 + ((g ^ ((hq2b >> 1) & 3)) << 4);
  int vboff[4];
#pragma unroll
  for (int n = 0; n < 4; ++n) {
    int el = (w & 3) * 64 + n * 16 + row;
    vboff[n] = el * 64 + ((g ^ ((el >> 1) & 3)) << 4);
  }

  f32x4 acc[2][4];
#pragma unroll
  for (int at = 0; at < 2; ++at)
#pragma unroll
    for (int n = 0; n < 4; ++n) acc[at][n] = (f32x4){0.f, 0.f, 0.f, 0.f};

  // produce P(tile) into pT[pp] from xT[bx1]
  auto produce = [&](int bx1, int pp) {
    const char* xbuf = smem + 49152 + bx1 * 4096;
    bf16x8 xa0 = *(const bf16x8*)(xbuf + xoffA);
    bf16x8 xa1 = *(const bf16x8*)(xbuf + xoffB);
    f32x4 sws = *(const f32x4*)(smem + 69632 + bx1 * 128 + swoff);
    f32x4 s4 = {0.f, 0.f, 0.f, 0.f};
    s4 = __builtin_amdgcn_mfma_f32_16x16x32_bf16(xa0, ya0, s4, 0, 0, 0);
    s4 = __builtin_amdgcn_mfma_f32_16x16x32_bf16(xa1, ya1, s4, 0, 0, 0);
    unsigned u0 = (unsigned)(unsigned short)f2b(__builtin_amdgcn_exp2f(s4[0]) * sws[0]) |
                  ((unsigned)(unsigned short)f2b(__builtin_amdgcn_exp2f(s4[1]) * sws[1]) << 16);
    unsigned u1 = (unsigned)(unsigned short)f2b(__builtin_amdgcn_exp2f(s4[2]) * sws[2]) |
                  ((unsigned)(unsigned short)f2b(__builtin_amdgcn_exp2f(s4[3]) * sws[3]) << 16);
    *(unsigned long long*)(smem + 61440 + pp * 4096 + poff_w) =
        (unsigned long long)u0 | ((unsigned long long)u1 << 32);
  };

  // consume: acc += pT[pp] x vT[rbv]
  auto consume = [&](int rbv, int pp) {
    const char* vbuf = smem + rbv * 16384;
    const char* pbuf = smem + 61440 + pp * 4096;
    bf16x8 pa0 = *(const bf16x8*)(pbuf + paoffA);
    bf16x8 pa1 = *(const bf16x8*)(pbuf + paoffB);
    __builtin_amdgcn_s_setprio(1);
#pragma unroll
    for (int n = 0; n < 4; ++n) {
      bf16x8 vb = *(const bf16x8*)(vbuf + vboff[n]);
      acc[0][n] = __builtin_amdgcn_mfma_f32_16x16x32_bf16(pa0, vb, acc[0][n], 0, 0, 0);
      acc[1][n] = __builtin_amdgcn_mfma_f32_16x16x32_bf16(pa1, vb, acc[1][n], 0, 0, 0);
    }
    __builtin_amdgcn_s_setprio(0);
  };

  // ---- prologue: stage tiles 0,1; drain xT0,sw0,vT0,xT1,sw1 (vT1 stays in flight) ----
  stage(0, 0);
  stage(1, 1);
  asm volatile("s_waitcnt vmcnt(2)" ::: "memory");
  __builtin_amdgcn_s_barrier();
  produce(0, 0);  // P(0) -> pT[0]
  asm volatile("s_waitcnt lgkmcnt(0)" ::: "memory");
  __builtin_amdgcn_s_barrier();

  int rbv = 0, bx1 = 1, sb = 2, p = 0;
  for (int it = 0; it < NIT - 1; ++it) {
    if (it < NIT - 2) stage(sb, it + 2);
    produce(bx1, p ^ 1);   // P(it+1) -> pT[!p]   (reads xT[(it+1)%3])
    consume(rbv, p);       // acc += pT[p] x vT[it%3]
    if (it < NIT - 2)
      asm volatile("s_waitcnt vmcnt(2) lgkmcnt(0)" ::: "memory");
    else
      asm volatile("s_waitcnt vmcnt(0) lgkmcnt(0)" ::: "memory");
    __builtin_amdgcn_s_barrier();
    rbv = rbv == 2 ? 0 : rbv + 1;
    bx1 = bx1 == 2 ? 0 : bx1 + 1;
    sb = sb == 2 ? 0 : sb + 1;
    p ^= 1;
  }
  consume(rbv, p);  // tile 127

#pragma unroll
  for (int at = 0; at < 2; ++at)
#pragma unroll
    for (int n = 0; n < 4; ++n)
#pragma unroll
      for (int r = 0; r < 4; ++r) {
        int h = hb + (w >> 2) * 32 + at * 16 + 4 * g + r;
        int e = eb + (w & 3) * 64 + n * 16 + row;
        out[(bH + h) * (size_t)EN + e] = acc[at][n][r];
      }
}

// ================= fallback path (round-1 kernels, ws < 40.5 MB) =================
__global__ __launch_bounds__(256) void k_stats_o(const float* __restrict__ xd,
                                                 const float* __restrict__ yd,
                                                 float* __restrict__ mz) {
  const int b = blockIdx.y;
  const int w = threadIdx.x >> 6;
  const int lane = threadIdx.x & 63;
  const int row = lane & 15, g = lane >> 4;
  const int lb = blockIdx.x * 64 + w * 16;
  const float* xp = xd + ((size_t)b * LN + lb + row) * KN + g * 8;
  bf16x8 a0 = cvt8(xp), a1 = cvt8(xp + 32);
  float m[4], s[4];
#pragma unroll
  for (int r = 0; r < 4; ++r) { m[r] = -1e30f; s[r] = 0.f; }
  const float* ybp = yd + ((size_t)b * HN + row) * KN + g * 8;
  for (int h0 = 0; h0 < HN; h0 += 16) {
    bf16x8 b0 = cvt8(ybp + (size_t)h0 * KN);
    bf16x8 b1 = cvt8(ybp + (size_t)h0 * KN + 32);
    f32x4 acc = {0.f, 0.f, 0.f, 0.f};
    acc = __builtin_amdgcn_mfma_f32_16x16x32_bf16(a0, b0, acc, 0, 0, 0);
    acc = __builtin_amdgcn_mfma_f32_16x16x32_bf16(a1, b1, acc, 0, 0, 0);
#pragma unroll
    for (int r = 0; r < 4; ++r) {
      float v = acc[r] * 0.125f;
      float mn = fmaxf(m[r], v);
      s[r] = s[r] * __expf(m[r] - mn) + __expf(v - mn);
      m[r] = mn;
    }
  }
#pragma unroll
  for (int d = 1; d < 16; d <<= 1) {
#pragma unroll
    for (int r = 0; r < 4; ++r) {
      float mo = __shfl_xor(m[r], d);
      float so = __shfl_xor(s[r], d);
      float mn = fmaxf(m[r], mo);
      s[r] = s[r] * __expf(m[r] - mn) + so * __expf(mo - mn);
      m[r] = mn;
    }
  }
  if (row == 0) {
#pragma unroll
    for (int r = 0; r < 4; ++r) {
      size_t idx = (size_t)b * LN + lb + 4 * g + r;
      mz[idx] = m[r];
      mz[(size_t)BN * LN + idx] = 1.0f / s[r];
    }
  }
}

__global__ __launch_bounds__(512) void k_main_o(const float* __restrict__ vals,
                                                const float* __restrict__ xd,
                                                const float* __restrict__ yd,
                                                const float* __restrict__ mz,
                                                float* __restrict__ out) {
  __shared__ short vT[256][34];
  __shared__ short pT[128][34];
  __shared__ short xT[LT][72];
  __shared__ float smm[LT], smz[LT];
  const int b = blockIdx.z;
  const int hb = blockIdx.x * 128;
  const int eb = blockIdx.y * 256;
  const int tid = threadIdx.x;
  const int w = tid >> 6, lane = tid & 63;
  const int row = lane & 15, g = lane >> 4;
  const float* yp = yd + ((size_t)b * HN + hb + w * 16 + row) * KN + g * 8;
  bf16x8 ya0 = cvt8(yp), ya1 = cvt8(yp + 32);
  f32x4 acc[16];
#pragma unroll
  for (int n = 0; n < 16; ++n) acc[n] = (f32x4){0.f, 0.f, 0.f, 0.f};
  const float* mzb = mz + (size_t)b * LN;
  const float* rzb = mz + (size_t)BN * LN + (size_t)b * LN;
  for (int l0 = 0; l0 < LN; l0 += LT) {
    __syncthreads();
    {
      int xl = tid >> 4, xk = (tid & 15) * 4;
      f32x4 xv = *(const f32x4*)(xd + ((size_t)b * LN + l0 + xl) * KN + xk);
      union { short h[4]; int i[2]; } u;
      u.h[0] = f2b(xv[0]); u.h[1] = f2b(xv[1]); u.h[2] = f2b(xv[2]); u.h[3] = f2b(xv[3]);
      int* dst = (int*)(&xT[xl][xk]);
      dst[0] = u.i[0]; dst[1] = u.i[1];
    }
#pragma unroll
    for (int lp = 0; lp < 4; ++lp) {
      int vl = (tid >> 6) + lp * 8;
      const float* vrow = vals + ((size_t)b * LN + l0 + vl) * EN + eb;
#pragma unroll
      for (int u2 = 0; u2 < 4; ++u2) {
        int e = (tid & 63) + u2 * 64;
        vT[e][vl] = f2b(vrow[e]);
      }
    }
    if (tid < LT) { smm[tid] = mzb[l0 + tid]; smz[tid] = rzb[l0 + tid]; }
    __syncthreads();
#pragma unroll
    for (int t2 = 0; t2 < 2; ++t2) {
      const short* xr = &xT[t2 * 16 + row][0];
      bf16x8 xb0 = *(const bf16x8*)(xr + 8 * g);
      bf16x8 xb1 = *(const bf16x8*)(xr + 32 + 8 * g);
      f32x4 sa = {0.f, 0.f, 0.f, 0.f};
      sa = __builtin_amdgcn_mfma_f32_16x16x32_bf16(ya0, xb0, sa, 0, 0, 0);
      sa = __builtin_amdgcn_mfma_f32_16x16x32_bf16(ya1, xb1, sa, 0, 0, 0);
      int lcol = t2 * 16 + row;
      float mm = smm[lcol], zz = smz[lcol];
#pragma unroll
      for (int r = 0; r < 4; ++r) {
        float p2 = __expf(sa[r] * 0.125f - mm) * zz;
        pT[w * 16 + 4 * g + r][lcol] = f2b(p2);
      }
    }
    __syncthreads();
    bf16x8 pa;
    {
      const int* pi = (const int*)(&pT[w * 16 + row][0] + 8 * g);
      union { int i[4]; bf16x8 f; } u;
      u.i[0] = pi[0]; u.i[1] = pi[1]; u.i[2] = pi[2]; u.i[3] = pi[3];
      pa = u.f;
    }
#pragma unroll
    for (int n = 0; n < 16; ++n) {
      const int* vi = (const int*)(&vT[n * 16 + row][0] + 8 * g);
      union { int i[4]; bf16x8 f; } u;
      u.i[0] = vi[0]; u.i[1] = vi[1]; u.i[2] = vi[2]; u.i[3] = vi[3];
      acc[n] = __builtin_amdgcn_mfma_f32_16x16x32_bf16(pa, u.f, acc[n], 0, 0, 0);
    }
  }
#pragma unroll
  for (int n = 0; n < 16; ++n)
#pragma unroll
    for (int r = 0; r < 4; ++r) {
      int h = hb + w * 16 + 4 * g + r;
      int e = eb + n * 16 + row;
      out[((size_t)b * HN + h) * EN + e] = acc[n][r];
    }
}

extern "C" void kernel_launch(void* const* d_in, const int* in_sizes, int n_in,
                              void* d_out, int out_size, void* d_ws, size_t ws_size,
                              hipStream_t stream) {
  const float* vals = (const float*)d_in[2];
  const float* xd = (const float*)d_in[3];
  const float* yd = (const float*)d_in[4];
  float* out = (float*)d_out;

  if (ws_size >= 40501248ull) {
    char* wsb = (char*)d_ws;
    short* valsT = (short*)wsb;                       // 33554432 B
    short* xbuf  = (short*)(wsb + 33554432);          //  4194304 B
    short* ybuf  = (short*)(wsb + 37748736);          //  2097152 B
    float* ps    = (float*)(wsb + 39845888);          //   524288 B
    float* wv    = (float*)(wsb + 40370176);          //   131072 B

    prep_cvt2<<<dim3(1536), 256, 0, stream>>>(xd, xbuf, yd, ybuf);
    k_pv_stats<<<dim3(5120), 256, 0, stream>>>(vals, valsT, xbuf, ybuf, ps);
    k_comb<<<dim3(BN * LN / 256), 256, 0, stream>>>(ps, wv);
    k_main4<<<dim3(512), 512, 0, stream>>>(valsT, xbuf, ybuf, wv, out);
  } else {
    float* mz = (float*)d_ws;
    k_stats_o<<<dim3(LN / 64, BN), 256, 0, stream>>>(xd, yd, mz);
    k_main_o<<<dim3(HN / 128, EN / 256, BN), 512, 0, stream>>>(vals, xd, yd, mz, out);
  }
}